// Round 2
// baseline (478.452 us; speedup 1.0000x reference)
//
#include <hip/hip_runtime.h>
#include <hip/hip_fp16.h>

// Problem constants (B,C,H,W = 2,3,96,96; D=32)
#define BB 2
#define CC 3
#define NN 9216   // 96*96
#define DD 32

typedef _Float16 half8 __attribute__((ext_vector_type(8)));
typedef float float4v __attribute__((ext_vector_type(4)));

#define MFMA16(a, b, c) __builtin_amdgcn_mfma_f32_16x16x32_f16((a), (b), (c), 0, 0, 0)

// ---------------------------------------------------------------------------
// Prep 1: per-pixel 1x1 conv 3->32 for key (f) and query (g), stored
// TRANSPOSED as [B][N][D] fp16, SPLIT into hi + lo residual so QK^T can be
// computed to ~fp32 precision with 3 MFMAs (hi*hi + lo*hi + hi*lo).
// ---------------------------------------------------------------------------
__global__ __launch_bounds__(256) void prep_qk_kernel(
    const float* __restrict__ img,
    const float* __restrict__ kw, const float* __restrict__ kb,
    const float* __restrict__ qw, const float* __restrict__ qb,
    _Float16* __restrict__ fH, _Float16* __restrict__ fL,
    _Float16* __restrict__ gH, _Float16* __restrict__ gL)
{
    int id = blockIdx.x * blockDim.x + threadIdx.x;
    if (id >= BB * NN) return;
    int b = id / NN, n = id % NN;
    const float* xb = img + (size_t)b * CC * NN + n;
    float x0 = xb[0], x1 = xb[NN], x2 = xb[2 * NN];
    half8 fh[4], fl[4], gh[4], gl[4];
#pragma unroll
    for (int k = 0; k < 4; k++) {
#pragma unroll
        for (int j = 0; j < 8; j++) {
            int d = k * 8 + j;
            float fv = kw[d * 3 + 0] * x0 + kw[d * 3 + 1] * x1 + kw[d * 3 + 2] * x2 + kb[d];
            float gv = qw[d * 3 + 0] * x0 + qw[d * 3 + 1] * x1 + qw[d * 3 + 2] * x2 + qb[d];
            _Float16 fhi = (_Float16)fv;
            _Float16 ghi = (_Float16)gv;
            fh[k][j] = fhi; fl[k][j] = (_Float16)(fv - (float)fhi);
            gh[k][j] = ghi; gl[k][j] = (_Float16)(gv - (float)ghi);
        }
    }
    half8* fho = (half8*)(fH + (size_t)id * DD);
    half8* flo = (half8*)(fL + (size_t)id * DD);
    half8* gho = (half8*)(gH + (size_t)id * DD);
    half8* glo = (half8*)(gL + (size_t)id * DD);
#pragma unroll
    for (int k = 0; k < 4; k++) { fho[k] = fh[k]; flo[k] = fl[k]; gho[k] = gh[k]; glo[k] = gl[k]; }
}

// ---------------------------------------------------------------------------
// Prep 2: value (h) stored NATURAL [B][D][N] fp16 (n contiguous) so the PV
// B-fragment (8 consecutive n at fixed d) loads 16B contiguous.
// ---------------------------------------------------------------------------
__global__ __launch_bounds__(256) void prep_v_kernel(
    const float* __restrict__ img, const float* __restrict__ vw,
    const float* __restrict__ vb, _Float16* __restrict__ hV)
{
    int id = blockIdx.x * blockDim.x + threadIdx.x;
    if (id >= BB * DD * NN) return;
    int n = id % NN;
    int d = (id / NN) % DD;
    int b = id / (NN * DD);
    const float* xb = img + (size_t)b * CC * NN + n;
    float x0 = xb[0], x1 = xb[NN], x2 = xb[2 * NN];
    hV[id] = (_Float16)(vw[d * 3 + 0] * x0 + vw[d * 3 + 1] * x1 + vw[d * 3 + 2] * x2 + vb[d]);
}

// ---------------------------------------------------------------------------
// Flash attention: one wave per 16-query tile. Iterate keys in chunks of 64.
//   S-tile: 3x mfma_f32_16x16x32_f16 per 16-key block (split-fp16 hi/lo:
//           s = qh*kh + ql*kh + qh*kl) -> ~fp32-accurate scores.
//   C-layout: row m = quad*4+reg, col n = lane&15.
//   Online softmax per row via 16-lane __shfl_xor butterflies.
//   P -> LDS [16][72] fp16 (pad 72 breaks bank conflicts on b128 A-reads),
//   then PV: O[m][d] accumulated in 2 C-frags.
// ---------------------------------------------------------------------------
__global__ __launch_bounds__(64) void attn_kernel(
    const _Float16* __restrict__ fH, const _Float16* __restrict__ fL,
    const _Float16* __restrict__ gH, const _Float16* __restrict__ gL,
    const _Float16* __restrict__ hV,
    const float* __restrict__ ow, const float* __restrict__ ob,
    float* __restrict__ out)
{
    const int tile = blockIdx.x;           // 0 .. B*(N/16)-1
    const int b = tile / (NN / 16);
    const int m0 = (tile % (NN / 16)) * 16;
    const int lane = threadIdx.x;
    const int l16 = lane & 15;
    const int quad = lane >> 4;

    __shared__ __align__(16) _Float16 Plds[16 * 72];
    __shared__ float vlds[16 * 33];

    const _Float16* fHb = fH + (size_t)b * NN * DD;
    const _Float16* fLb = fL + (size_t)b * NN * DD;
    const _Float16* hb  = hV + (size_t)b * DD * NN;

    // Q A-fragments (hi + lo): A[m=l16][k=quad*8+j], held for the whole kernel.
    half8 qh = *(const half8*)(gH + ((size_t)b * NN + m0 + l16) * DD + quad * 8);
    half8 ql = *(const half8*)(gL + ((size_t)b * NN + m0 + l16) * DD + quad * 8);

    float4v acc0 = {0.f, 0.f, 0.f, 0.f};  // O[m][d],   d = l16
    float4v acc1 = {0.f, 0.f, 0.f, 0.f};  // O[m][d+16]
    float mrun[4], lrun[4];
#pragma unroll
    for (int r = 0; r < 4; r++) { mrun[r] = -1e30f; lrun[r] = 0.f; }

    const _Float16* vrow0 = hb + (size_t)l16 * NN;
    const _Float16* vrow1 = hb + (size_t)(l16 + 16) * NN;

    for (int n0 = 0; n0 < NN; n0 += 64) {
        // ---- scores: 4 blocks of 16 keys, 3 chained MFMAs each (hi/lo split)
        float4v s[4];
#pragma unroll
        for (int blk = 0; blk < 4; blk++) {
            size_t koff = (size_t)(n0 + blk * 16 + l16) * DD + quad * 8;
            half8 kh = *(const half8*)(fHb + koff);
            half8 kl = *(const half8*)(fLb + koff);
            float4v z = {0.f, 0.f, 0.f, 0.f};
            float4v t = MFMA16(qh, kl, z);
            t = MFMA16(ql, kh, t);
            s[blk] = MFMA16(qh, kh, t);
        }
        // ---- row max over 64 keys (4 blocks + 16 cols across lanes)
        float mnew[4], alpha[4], rsum[4];
#pragma unroll
        for (int r = 0; r < 4; r++) {
            float mx = fmaxf(fmaxf(s[0][r], s[1][r]), fmaxf(s[2][r], s[3][r]));
#pragma unroll
            for (int off = 1; off < 16; off <<= 1)
                mx = fmaxf(mx, __shfl_xor(mx, off, 64));
            mnew[r] = fmaxf(mrun[r], mx);
            alpha[r] = __expf(mrun[r] - mnew[r]);
            rsum[r] = 0.f;
        }
        // ---- P = exp(s - mnew): accumulate row sums, stage to LDS as fp16
#pragma unroll
        for (int blk = 0; blk < 4; blk++) {
#pragma unroll
            for (int r = 0; r < 4; r++) {
                float p = __expf(s[blk][r] - mnew[r]);
                rsum[r] += p;
                Plds[(quad * 4 + r) * 72 + blk * 16 + l16] = (_Float16)p;
            }
        }
#pragma unroll
        for (int r = 0; r < 4; r++) {
            float t = rsum[r];
#pragma unroll
            for (int off = 1; off < 16; off <<= 1)
                t += __shfl_xor(t, off, 64);
            lrun[r] = lrun[r] * alpha[r] + t;
            mrun[r] = mnew[r];
            acc0[r] *= alpha[r];
            acc1[r] *= alpha[r];
        }
        __syncthreads();
        // ---- PV: O[m][d] += P-tile (A-layout from LDS) * V (B from global)
#pragma unroll
        for (int t = 0; t < 2; t++) {
            half8 pf = *(const half8*)(&Plds[l16 * 72 + t * 32 + quad * 8]);
            half8 v0 = *(const half8*)(vrow0 + n0 + t * 32 + quad * 8);
            half8 v1 = *(const half8*)(vrow1 + n0 + t * 32 + quad * 8);
            acc0 = MFMA16(pf, v0, acc0);
            acc1 = MFMA16(pf, v1, acc1);
        }
        __syncthreads();
    }

    // ---- epilogue: v = acc / l  -> LDS, then D->3 projection + clamp
#pragma unroll
    for (int r = 0; r < 4; r++) {
        float inv = 1.f / lrun[r];
        vlds[(quad * 4 + r) * 33 + l16] = acc0[r] * inv;
        vlds[(quad * 4 + r) * 33 + 16 + l16] = acc1[r] * inv;
    }
    __syncthreads();
    if (lane < 48) {
        int m = lane & 15, c = lane >> 4;
        float o = ob[c];
#pragma unroll
        for (int d = 0; d < DD; d++)
            o += ow[c * DD + d] * vlds[m * 33 + d];
        o = fminf(1.f, fmaxf(-1.f, o));
        out[((size_t)b * CC + c) * NN + m0 + m] = o;
    }
}

extern "C" void kernel_launch(void* const* d_in, const int* in_sizes, int n_in,
                              void* d_out, int out_size, void* d_ws, size_t ws_size,
                              hipStream_t stream) {
    const float* img = (const float*)d_in[0];
    const float* kw  = (const float*)d_in[1];
    const float* kb  = (const float*)d_in[2];
    const float* qw  = (const float*)d_in[3];
    const float* qb  = (const float*)d_in[4];
    const float* vw  = (const float*)d_in[5];
    const float* vb  = (const float*)d_in[6];
    const float* ow  = (const float*)d_in[7];
    const float* ob  = (const float*)d_in[8];
    float* out = (float*)d_out;

    // Workspace: fH,fL,gH,gL ([B][N][D] fp16) + hV ([B][D][N] fp16) = 5.9 MB
    const size_t sz = (size_t)BB * NN * DD;
    _Float16* fH = (_Float16*)d_ws;
    _Float16* fL = fH + sz;
    _Float16* gH = fL + sz;
    _Float16* gL = gH + sz;
    _Float16* hV = gL + sz;

    prep_qk_kernel<<<(BB * NN + 255) / 256, 256, 0, stream>>>(img, kw, kb, qw, qb, fH, fL, gH, gL);
    prep_v_kernel<<<(BB * DD * NN + 255) / 256, 256, 0, stream>>>(img, vw, vb, hV);
    attn_kernel<<<BB * (NN / 16), 64, 0, stream>>>(fH, fL, gH, gL, hV, ow, ob, out);
}

// Round 3
// 240.751 us; speedup vs baseline: 1.9873x; 1.9873x over previous
//
#include <hip/hip_runtime.h>
#include <hip/hip_fp16.h>

// Problem constants (B,C,H,W = 2,3,96,96; D=32)
#define BB 2
#define CC 3
#define NN 9216   // 96*96
#define DD 32
#define NSPLIT 4                      // waves per block, split over keys
#define KEYS_PER_WAVE (NN / NSPLIT)   // 2304
#define CHUNKS (KEYS_PER_WAVE / 64)   // 36

typedef _Float16 half8 __attribute__((ext_vector_type(8)));
typedef _Float16 half4v __attribute__((ext_vector_type(4)));
typedef float float4v __attribute__((ext_vector_type(4)));

#define MFMA16(a, b, c) __builtin_amdgcn_mfma_f32_16x16x32_f16((a), (b), (c), 0, 0, 0)

// ---------------------------------------------------------------------------
// Prep 1: 1x1 conv 3->32 for key (f) / query (g), stored [B][N][D] fp16,
// split hi + lo residual for ~fp32-accurate QK^T via 3 MFMAs.
// ---------------------------------------------------------------------------
__global__ __launch_bounds__(256) void prep_qk_kernel(
    const float* __restrict__ img,
    const float* __restrict__ kw, const float* __restrict__ kb,
    const float* __restrict__ qw, const float* __restrict__ qb,
    _Float16* __restrict__ fH, _Float16* __restrict__ fL,
    _Float16* __restrict__ gH, _Float16* __restrict__ gL)
{
    int id = blockIdx.x * blockDim.x + threadIdx.x;
    if (id >= BB * NN) return;
    int b = id / NN, n = id % NN;
    const float* xb = img + (size_t)b * CC * NN + n;
    float x0 = xb[0], x1 = xb[NN], x2 = xb[2 * NN];
    half8 fh[4], fl[4], gh[4], gl[4];
#pragma unroll
    for (int k = 0; k < 4; k++) {
#pragma unroll
        for (int j = 0; j < 8; j++) {
            int d = k * 8 + j;
            float fv = kw[d * 3 + 0] * x0 + kw[d * 3 + 1] * x1 + kw[d * 3 + 2] * x2 + kb[d];
            float gv = qw[d * 3 + 0] * x0 + qw[d * 3 + 1] * x1 + qw[d * 3 + 2] * x2 + qb[d];
            _Float16 fhi = (_Float16)fv;
            _Float16 ghi = (_Float16)gv;
            fh[k][j] = fhi; fl[k][j] = (_Float16)(fv - (float)fhi);
            gh[k][j] = ghi; gl[k][j] = (_Float16)(gv - (float)ghi);
        }
    }
    half8* fho = (half8*)(fH + (size_t)id * DD);
    half8* flo = (half8*)(fL + (size_t)id * DD);
    half8* gho = (half8*)(gH + (size_t)id * DD);
    half8* glo = (half8*)(gL + (size_t)id * DD);
#pragma unroll
    for (int k = 0; k < 4; k++) { fho[k] = fh[k]; flo[k] = fl[k]; gho[k] = gh[k]; glo[k] = gl[k]; }
}

// ---------------------------------------------------------------------------
// Prep 2: value (h) stored [B][D][N] fp16, vectorized: 8 pixels per thread,
// half8 (16B) coalesced stores.
// ---------------------------------------------------------------------------
__global__ __launch_bounds__(256) void prep_v_kernel(
    const float* __restrict__ img, const float* __restrict__ vw,
    const float* __restrict__ vb, _Float16* __restrict__ hV)
{
    int id = blockIdx.x * blockDim.x + threadIdx.x;
    const int N8 = NN / 8;
    if (id >= BB * DD * N8) return;
    int n8 = id % N8;
    int d = (id / N8) % DD;
    int b = id / (N8 * DD);
    const float* xb = img + (size_t)b * CC * NN + n8 * 8;
    float w0 = vw[d * 3 + 0], w1 = vw[d * 3 + 1], w2 = vw[d * 3 + 2], bv = vb[d];
    half8 hv;
#pragma unroll
    for (int j = 0; j < 8; j++)
        hv[j] = (_Float16)(w0 * xb[j] + w1 * xb[NN + j] + w2 * xb[2 * NN + j] + bv);
    *(half8*)(hV + (size_t)id * 8) = hv;
}

// ---------------------------------------------------------------------------
// Flash attention, split-K x4: block = 4 waves, each wave owns 2304 keys of
// the same 16-query tile; fp32 log-sum-exp merge at the end.
//   S-tile ORIENTATION: A = K-frag, B = Q-frag  =>  C[row=n_local, col=m].
//   Per lane: col m = lane&15 fixed; 16 s-values at n = blk*16+quad*4+r.
//   Softmax over keys = 15 local fmax/adds + 2 cross-quad shuffles; stats
//   (mrun/lrun/alpha) are lane-scalars, identical across quads.
//   P stored [m][n] (pad 72) via packed ds_write_b64; PV A-frag b128 reads.
//   No barriers in the chunk loop: P region is wave-private, per-wave DS ops
//   execute in order; asm memory clobbers stop compiler reordering.
// ---------------------------------------------------------------------------
__global__ __launch_bounds__(256, 5) void attn_kernel(
    const _Float16* __restrict__ fH, const _Float16* __restrict__ fL,
    const _Float16* __restrict__ gH, const _Float16* __restrict__ gL,
    const _Float16* __restrict__ hV,
    const float* __restrict__ ow, const float* __restrict__ ob,
    float* __restrict__ out)
{
    const int tile = blockIdx.x;           // 0 .. B*(N/16)-1
    const int b = tile / (NN / 16);
    const int m0 = (tile % (NN / 16)) * 16;
    const int tid = threadIdx.x;
    const int w = tid >> 6;                // wave id 0..3
    const int lane = tid & 63;
    const int l16 = lane & 15;
    const int quad = lane >> 4;

    __shared__ __align__(16) _Float16 Plds[NSPLIT][16 * 72];
    __shared__ float accbuf[NSPLIT][16][33];
    __shared__ float mbuf[NSPLIT][16];
    __shared__ float lbuf[NSPLIT][16];
    __shared__ float vlds[16 * 33];

    const _Float16* fHb = fH + (size_t)b * NN * DD;
    const _Float16* fLb = fL + (size_t)b * NN * DD;
    const _Float16* hb  = hV + (size_t)b * DD * NN;

    // Q B-fragments (hi + lo): B[k=quad*8+j][col=m=l16]
    half8 qh = *(const half8*)(gH + ((size_t)b * NN + m0 + l16) * DD + quad * 8);
    half8 ql = *(const half8*)(gL + ((size_t)b * NN + m0 + l16) * DD + quad * 8);

    float4v acc0 = {0.f, 0.f, 0.f, 0.f};  // O[m=quad*4+r][d=l16]
    float4v acc1 = {0.f, 0.f, 0.f, 0.f};  // O[m=quad*4+r][d=l16+16]
    float mrun = -1e30f, lrun = 0.f;      // per-lane stats for column m=l16

    const int nbase = w * KEYS_PER_WAVE;
    const _Float16* vrow0 = hb + (size_t)l16 * NN + nbase;
    const _Float16* vrow1 = hb + (size_t)(l16 + 16) * NN + nbase;
    const _Float16* kHp = fHb + (size_t)(nbase + l16) * DD + quad * 8;
    const _Float16* kLp = fLb + (size_t)(nbase + l16) * DD + quad * 8;
    _Float16* Pw = &Plds[w][0];

    for (int c = 0; c < CHUNKS; ++c) {
        // ---- scores for 64 keys: A = K (rows n), B = Q (cols m)
        float4v s[4];
#pragma unroll
        for (int blk = 0; blk < 4; blk++) {
            size_t off = (size_t)(c * 64 + blk * 16) * DD;
            half8 kh = *(const half8*)(kHp + off);
            half8 kl = *(const half8*)(kLp + off);
            float4v z = {0.f, 0.f, 0.f, 0.f};
            float4v t = MFMA16(kh, ql, z);
            t = MFMA16(kl, qh, t);
            s[blk] = MFMA16(kh, qh, t);
        }
        // ---- max over 64 keys: 15 local fmax + 2 cross-quad shuffles
        float mb[4];
#pragma unroll
        for (int blk = 0; blk < 4; blk++)
            mb[blk] = fmaxf(fmaxf(s[blk][0], s[blk][1]), fmaxf(s[blk][2], s[blk][3]));
        float mx = fmaxf(fmaxf(mb[0], mb[1]), fmaxf(mb[2], mb[3]));
        mx = fmaxf(mx, __shfl_xor(mx, 16, 64));
        mx = fmaxf(mx, __shfl_xor(mx, 32, 64));
        float mnew = fmaxf(mrun, mx);
        // ---- P = exp(s - mnew), row sum
        float rsum = 0.f;
        half4v pv[4];
#pragma unroll
        for (int blk = 0; blk < 4; blk++) {
#pragma unroll
            for (int r = 0; r < 4; r++) {
                float p = __expf(s[blk][r] - mnew);
                rsum += p;
                pv[blk][r] = (_Float16)p;
            }
        }
        float t0 = __shfl_xor(rsum, 16, 64); rsum += t0;
        float t1 = __shfl_xor(rsum, 32, 64); rsum += t1;
        // ---- rescale accumulators only when the max moved (wave-collective)
        if (__any(mnew > mrun)) {
            float alpha = __expf(mrun - mnew);
            float aT[4];
#pragma unroll
            for (int r = 0; r < 4; r++) aT[r] = __shfl(alpha, quad * 4 + r, 64);
#pragma unroll
            for (int r = 0; r < 4; r++) { acc0[r] *= aT[r]; acc1[r] *= aT[r]; }
            lrun = lrun * alpha + rsum;
            mrun = mnew;
        } else {
            lrun += rsum;
        }
        // ---- stage P: [m=l16][n = blk*16 + quad*4 + r], packed 8B writes
#pragma unroll
        for (int blk = 0; blk < 4; blk++)
            *(half4v*)(Pw + l16 * 72 + blk * 16 + quad * 4) = pv[blk];
        asm volatile("" ::: "memory");   // order P-writes before P-reads (wave-private)
        // ---- PV: A = P[m][n] (b128 from LDS), B = V[n][d] (global)
#pragma unroll
        for (int t = 0; t < 2; t++) {
            half8 pf = *(const half8*)(Pw + l16 * 72 + t * 32 + quad * 8);
            half8 v0 = *(const half8*)(vrow0 + c * 64 + t * 32 + quad * 8);
            half8 v1 = *(const half8*)(vrow1 + c * 64 + t * 32 + quad * 8);
            acc0 = MFMA16(pf, v0, acc0);
            acc1 = MFMA16(pf, v1, acc1);
        }
        asm volatile("" ::: "memory");   // order P-reads before next chunk's writes
    }

    // ---- write per-wave partials (fp32) for the split-K merge
    mbuf[w][l16] = mrun;                  // redundant across quads, same value
    lbuf[w][l16] = lrun;
#pragma unroll
    for (int r = 0; r < 4; r++) {
        accbuf[w][quad * 4 + r][l16]      = acc0[r];
        accbuf[w][quad * 4 + r][l16 + 16] = acc1[r];
    }
    __syncthreads();

    // ---- merge 4 waves: 512 (m,d) elems by 256 threads
#pragma unroll
    for (int e = tid; e < 16 * DD; e += 256) {
        int m = e >> 5, d = e & 31;
        float m0v = mbuf[0][m], m1v = mbuf[1][m], m2v = mbuf[2][m], m3v = mbuf[3][m];
        float M = fmaxf(fmaxf(m0v, m1v), fmaxf(m2v, m3v));
        float e0 = __expf(m0v - M), e1 = __expf(m1v - M),
              e2 = __expf(m2v - M), e3 = __expf(m3v - M);
        float L = lbuf[0][m] * e0 + lbuf[1][m] * e1 + lbuf[2][m] * e2 + lbuf[3][m] * e3;
        float num = accbuf[0][m][d] * e0 + accbuf[1][m][d] * e1 +
                    accbuf[2][m][d] * e2 + accbuf[3][m][d] * e3;
        vlds[m * 33 + d] = num / L;
    }
    __syncthreads();

    // ---- epilogue: D->3 projection + clamp (48 threads)
    if (tid < 48) {
        int m = tid & 15, c = tid >> 4;
        float o = ob[c];
#pragma unroll
        for (int d = 0; d < DD; d++)
            o += ow[c * DD + d] * vlds[m * 33 + d];
        o = fminf(1.f, fmaxf(-1.f, o));
        out[((size_t)b * CC + c) * NN + m0 + m] = o;
    }
}

extern "C" void kernel_launch(void* const* d_in, const int* in_sizes, int n_in,
                              void* d_out, int out_size, void* d_ws, size_t ws_size,
                              hipStream_t stream) {
    const float* img = (const float*)d_in[0];
    const float* kw  = (const float*)d_in[1];
    const float* kb  = (const float*)d_in[2];
    const float* qw  = (const float*)d_in[3];
    const float* qb  = (const float*)d_in[4];
    const float* vw  = (const float*)d_in[5];
    const float* vb  = (const float*)d_in[6];
    const float* ow  = (const float*)d_in[7];
    const float* ob  = (const float*)d_in[8];
    float* out = (float*)d_out;

    // Workspace: fH,fL,gH,gL ([B][N][D] fp16) + hV ([B][D][N] fp16) = 5.9 MB
    const size_t sz = (size_t)BB * NN * DD;
    _Float16* fH = (_Float16*)d_ws;
    _Float16* fL = fH + sz;
    _Float16* gH = fL + sz;
    _Float16* gL = gH + sz;
    _Float16* hV = gL + sz;

    prep_qk_kernel<<<(BB * NN + 255) / 256, 256, 0, stream>>>(img, kw, kb, qw, qb, fH, fL, gH, gL);
    prep_v_kernel<<<(BB * DD * NN / 8 + 255) / 256, 256, 0, stream>>>(img, vw, vb, hV);
    attn_kernel<<<BB * (NN / 16), 256, 0, stream>>>(fH, fL, gH, gL, hV, ow, ob, out);
}

// Round 5
// 239.074 us; speedup vs baseline: 2.0013x; 1.0070x over previous
//
#include <hip/hip_runtime.h>
#include <hip/hip_fp16.h>

// Problem constants (B,C,H,W = 2,3,96,96; D=32)
#define BB 2
#define CC 3
#define NN 9216   // 96*96
#define DD 32
#define NSPLIT 8                      // waves per block, split over keys
#define KEYS_PER_WAVE (NN / NSPLIT)   // 1152
#define CHUNKS (KEYS_PER_WAVE / 64)   // 18
#define L2E 1.44269504f

typedef _Float16 half8 __attribute__((ext_vector_type(8)));
typedef _Float16 half4v __attribute__((ext_vector_type(4)));
typedef __fp16 fp16x2 __attribute__((ext_vector_type(2)));
typedef float float4v __attribute__((ext_vector_type(4)));

#define MFMA16(a, b, c) __builtin_amdgcn_mfma_f32_16x16x32_f16((a), (b), (c), 0, 0, 0)

// ---------------------------------------------------------------------------
// Fused prep. Blocks [0,288): QK — thread per (b, n, part), part = 8 channels
// of both f and g, hi/lo split, 16B coalesced stores. Blocks [288,576): V —
// thread per (b, d, 8 pixels), [B][D][N] fp16, 16B stores.
// ---------------------------------------------------------------------------
__global__ __launch_bounds__(256) void prep_kernel(
    const float* __restrict__ img,
    const float* __restrict__ kw, const float* __restrict__ kb,
    const float* __restrict__ qw, const float* __restrict__ qb,
    const float* __restrict__ vw, const float* __restrict__ vb,
    _Float16* __restrict__ fH, _Float16* __restrict__ fL,
    _Float16* __restrict__ gH, _Float16* __restrict__ gL,
    _Float16* __restrict__ hV)
{
    int bid = blockIdx.x;
    if (bid < 288) {
        int id = bid * 256 + threadIdx.x;          // [0, BB*NN*4)
        int part = id & 3;
        int n = (id >> 2) % NN;
        int b = (id >> 2) / NN;
        const float* xb = img + (size_t)b * CC * NN + n;
        float x0 = xb[0], x1 = xb[NN], x2 = xb[2 * NN];
        half8 fh, fl, gh, gl;
#pragma unroll
        for (int j = 0; j < 8; j++) {
            int d = part * 8 + j;
            float fv = kw[d * 3 + 0] * x0 + kw[d * 3 + 1] * x1 + kw[d * 3 + 2] * x2 + kb[d];
            float gv = qw[d * 3 + 0] * x0 + qw[d * 3 + 1] * x1 + qw[d * 3 + 2] * x2 + qb[d];
            _Float16 fhi = (_Float16)fv;
            _Float16 ghi = (_Float16)gv;
            fh[j] = fhi; fl[j] = (_Float16)(fv - (float)fhi);
            gh[j] = ghi; gl[j] = (_Float16)(gv - (float)ghi);
        }
        size_t off = ((size_t)b * NN + n) * DD + part * 8;
        *(half8*)(fH + off) = fh;
        *(half8*)(fL + off) = fl;
        *(half8*)(gH + off) = gh;
        *(half8*)(gL + off) = gl;
    } else {
        int id = (bid - 288) * 256 + threadIdx.x;  // [0, BB*DD*NN/8)
        const int N8 = NN / 8;
        int n8 = id % N8;
        int d = (id / N8) % DD;
        int b = id / (N8 * DD);
        const float* xb = img + (size_t)b * CC * NN + n8 * 8;
        float w0 = vw[d * 3 + 0], w1 = vw[d * 3 + 1], w2 = vw[d * 3 + 2], bv = vb[d];
        half8 hv;
#pragma unroll
        for (int j = 0; j < 8; j++)
            hv[j] = (_Float16)(w0 * xb[j] + w1 * xb[NN + j] + w2 * xb[2 * NN + j] + bv);
        *(half8*)(hV + (size_t)id * 8) = hv;
    }
}

// ---------------------------------------------------------------------------
// Flash attention, split-K x8: block = 8 waves (512 thr), each wave owns 1152
// keys of one 16-query tile; fp32 log-sum-exp merge at the end.
//   S-tile: A = K-frag, B = Q-frag => C[row=n_local, col=m]; lane stats are
//   per-column (m=l16) scalars. Split-fp16 scores via 3 chained MFMAs.
//   V-fragments hoisted to chunk top; K loads batched (MLP) — launch_bounds
//   (512,6) gives the allocator 85 VGPRs to keep ~8 b128 loads in flight.
//   P staged [m][n] (stride 72, structural-minimum banking) wave-privately;
//   no barriers in the chunk loop.
// ---------------------------------------------------------------------------
__global__ __launch_bounds__(512, 6) void attn_kernel(
    const _Float16* __restrict__ fH, const _Float16* __restrict__ fL,
    const _Float16* __restrict__ gH, const _Float16* __restrict__ gL,
    const _Float16* __restrict__ hV,
    const float* __restrict__ ow, const float* __restrict__ ob,
    float* __restrict__ out)
{
    const int tile = blockIdx.x;           // 0 .. B*(N/16)-1
    const int b = tile / (NN / 16);
    const int m0 = (tile % (NN / 16)) * 16;
    const int tid = threadIdx.x;
    const int w = tid >> 6;                // wave id 0..7
    const int lane = tid & 63;
    const int l16 = lane & 15;
    const int quad = lane >> 4;

    __shared__ __align__(16) _Float16 Plds[NSPLIT][16 * 72];
    __shared__ float accbuf[NSPLIT][16][33];
    __shared__ float mbuf[NSPLIT][16];
    __shared__ float lbuf[NSPLIT][16];
    __shared__ float vlds[16 * 33];

    // Q B-fragments (hi + lo): B[k=quad*8+j][col=m=l16]
    half8 qh = *(const half8*)(gH + ((size_t)b * NN + m0 + l16) * DD + quad * 8);
    half8 ql = *(const half8*)(gL + ((size_t)b * NN + m0 + l16) * DD + quad * 8);

    float4v acc0 = {0.f, 0.f, 0.f, 0.f};  // O[m=quad*4+r][d=l16]
    float4v acc1 = {0.f, 0.f, 0.f, 0.f};  // O[m=quad*4+r][d=l16+16]
    float mrun = -1e30f, lrun = 0.f;      // per-lane stats for column m=l16

    const int nbase = w * KEYS_PER_WAVE;
    const _Float16* hb = hV + (size_t)b * DD * NN;
    const _Float16* vp0 = hb + (size_t)l16 * NN + nbase + quad * 8;
    const _Float16* vp1 = hb + (size_t)(l16 + 16) * NN + nbase + quad * 8;
    const _Float16* khp = fH + ((size_t)b * NN + nbase + l16) * DD + quad * 8;
    const _Float16* klp = fL + ((size_t)b * NN + nbase + l16) * DD + quad * 8;
    _Float16* Pw = &Plds[w][0];

    for (int c = 0; c < CHUNKS; ++c) {
        // ---- V fragments for this chunk (hoisted: latency overlaps S phase)
        half8 v00 = *(const half8*)(vp0);
        half8 v01 = *(const half8*)(vp0 + 32);
        half8 v10 = *(const half8*)(vp1);
        half8 v11 = *(const half8*)(vp1 + 32);
        // ---- K fragments, batched loads
        half8 ka[4], kl[4];
#pragma unroll
        for (int blk = 0; blk < 4; blk++) {
            ka[blk] = *(const half8*)(khp + (size_t)blk * 16 * DD);
            kl[blk] = *(const half8*)(klp + (size_t)blk * 16 * DD);
        }
        // ---- scores: A = K (rows n), B = Q (cols m); split-fp16 3-MFMA chain
        float4v s[4];
#pragma unroll
        for (int blk = 0; blk < 4; blk++) {
            float4v z = {0.f, 0.f, 0.f, 0.f};
            float4v t = MFMA16(ka[blk], ql, z);
            t = MFMA16(kl[blk], qh, t);
            s[blk] = MFMA16(ka[blk], qh, t);
        }
        // ---- max over 64 keys: local tree + 2 cross-quad shuffles
        float mb0 = fmaxf(fmaxf(s[0][0], s[0][1]), fmaxf(s[0][2], s[0][3]));
        float mb1 = fmaxf(fmaxf(s[1][0], s[1][1]), fmaxf(s[1][2], s[1][3]));
        float mb2 = fmaxf(fmaxf(s[2][0], s[2][1]), fmaxf(s[2][2], s[2][3]));
        float mb3 = fmaxf(fmaxf(s[3][0], s[3][1]), fmaxf(s[3][2], s[3][3]));
        float mx = fmaxf(fmaxf(mb0, mb1), fmaxf(mb2, mb3));
        mx = fmaxf(mx, __shfl_xor(mx, 16, 64));
        mx = fmaxf(mx, __shfl_xor(mx, 32, 64));
        float mnew = fmaxf(mrun, mx);
        float ml = mnew * L2E;
        // ---- P = exp2(s*log2e - ml); pack with cvt_pkrtz; tree row-sum
        float ps[4][4];
        half4v pv[4];
#pragma unroll
        for (int blk = 0; blk < 4; blk++) {
#pragma unroll
            for (int r = 0; r < 4; r++)
                ps[blk][r] = __builtin_amdgcn_exp2f(s[blk][r] * L2E - ml);
            union { fp16x2 h2[2]; half4v h4; } u;
            u.h2[0] = __builtin_amdgcn_cvt_pkrtz(ps[blk][0], ps[blk][1]);
            u.h2[1] = __builtin_amdgcn_cvt_pkrtz(ps[blk][2], ps[blk][3]);
            pv[blk] = u.h4;
        }
        float r0 = (ps[0][0] + ps[0][1]) + (ps[0][2] + ps[0][3]);
        float r1 = (ps[1][0] + ps[1][1]) + (ps[1][2] + ps[1][3]);
        float r2 = (ps[2][0] + ps[2][1]) + (ps[2][2] + ps[2][3]);
        float r3 = (ps[3][0] + ps[3][1]) + (ps[3][2] + ps[3][3]);
        float rsum = (r0 + r1) + (r2 + r3);
        rsum += __shfl_xor(rsum, 16, 64);
        rsum += __shfl_xor(rsum, 32, 64);
        // ---- rescale accumulators only when the max moved (wave-collective)
        if (__any(mnew > mrun)) {
            float alpha = __builtin_amdgcn_exp2f(mrun * L2E - ml);
            float aT[4];
#pragma unroll
            for (int r = 0; r < 4; r++) aT[r] = __shfl(alpha, quad * 4 + r, 64);
#pragma unroll
            for (int r = 0; r < 4; r++) { acc0[r] *= aT[r]; acc1[r] *= aT[r]; }
            lrun = lrun * alpha + rsum;
            mrun = mnew;
        } else {
            lrun += rsum;
        }
        // ---- stage P: [m=l16][n = blk*16 + quad*4 + r], packed 8B writes
#pragma unroll
        for (int blk = 0; blk < 4; blk++)
            *(half4v*)(Pw + l16 * 72 + blk * 16 + quad * 4) = pv[blk];
        asm volatile("" ::: "memory");   // order P-writes before P-reads (wave-private)
        // ---- PV: A = P[m][n] (b128 from LDS), B = V[n][d]
        half8 pf0 = *(const half8*)(Pw + l16 * 72 + quad * 8);
        half8 pf1 = *(const half8*)(Pw + l16 * 72 + 32 + quad * 8);
        acc0 = MFMA16(pf0, v00, acc0);
        acc1 = MFMA16(pf0, v10, acc1);
        acc0 = MFMA16(pf1, v01, acc0);
        acc1 = MFMA16(pf1, v11, acc1);
        asm volatile("" ::: "memory");   // order P-reads before next chunk's writes
        khp += 64 * DD; klp += 64 * DD; vp0 += 64; vp1 += 64;
    }

    // ---- write per-wave partials (fp32) for the split-K merge
    mbuf[w][l16] = mrun;                  // redundant across quads, same value
    lbuf[w][l16] = lrun;
#pragma unroll
    for (int r = 0; r < 4; r++) {
        accbuf[w][quad * 4 + r][l16]      = acc0[r];
        accbuf[w][quad * 4 + r][l16 + 16] = acc1[r];
    }
    __syncthreads();

    // ---- merge 8 waves: 512 (m,d) elems, one per thread
    {
        int m = tid >> 5, d = tid & 31;
        float M = mbuf[0][m];
#pragma unroll
        for (int s2 = 1; s2 < NSPLIT; s2++) M = fmaxf(M, mbuf[s2][m]);
        float L = 0.f, num = 0.f;
#pragma unroll
        for (int s2 = 0; s2 < NSPLIT; s2++) {
            float e = __expf(mbuf[s2][m] - M);
            L += lbuf[s2][m] * e;
            num += accbuf[s2][m][d] * e;
        }
        vlds[m * 33 + d] = num / L;
    }
    __syncthreads();

    // ---- epilogue: D->3 projection + clamp (48 threads)
    if (tid < 48) {
        int m = tid & 15, c = tid >> 4;
        float o = ob[c];
#pragma unroll
        for (int d = 0; d < DD; d++)
            o += ow[c * DD + d] * vlds[m * 33 + d];
        o = fminf(1.f, fmaxf(-1.f, o));
        out[((size_t)b * CC + c) * NN + m0 + m] = o;
    }
}

extern "C" void kernel_launch(void* const* d_in, const int* in_sizes, int n_in,
                              void* d_out, int out_size, void* d_ws, size_t ws_size,
                              hipStream_t stream) {
    const float* img = (const float*)d_in[0];
    const float* kw  = (const float*)d_in[1];
    const float* kb  = (const float*)d_in[2];
    const float* qw  = (const float*)d_in[3];
    const float* qb  = (const float*)d_in[4];
    const float* vw  = (const float*)d_in[5];
    const float* vb  = (const float*)d_in[6];
    const float* ow  = (const float*)d_in[7];
    const float* ob  = (const float*)d_in[8];
    float* out = (float*)d_out;

    // Workspace: fH,fL,gH,gL ([B][N][D] fp16) + hV ([B][D][N] fp16) = 5.9 MB
    const size_t sz = (size_t)BB * NN * DD;
    _Float16* fH = (_Float16*)d_ws;
    _Float16* fL = fH + sz;
    _Float16* gH = fL + sz;
    _Float16* gL = gH + sz;
    _Float16* hV = gL + sz;

    prep_kernel<<<576, 256, 0, stream>>>(img, kw, kb, qw, qb, vw, vb, fH, fL, gH, gL, hV);
    attn_kernel<<<BB * (NN / 16), 512, 0, stream>>>(fH, fL, gH, gL, hV, ow, ob, out);
}